// Round 12
// baseline (1739.985 us; speedup 1.0000x reference)
//
#include <hip/hip_runtime.h>
#include <hip/hip_bf16.h>
#include <math.h>

// EquivariantDiffusionModel on MI355X — round 12.
// KB was latency-bound (occupancy 40%, all pipes <40%, ~70% stall per block-slot),
// pinned at 4 blocks/CU by 35KB LDS + 128-reg footprint. This round: m-half split —
// grid 8192 = pass x (b,i) x m-half; 16KB A_s, 32-AGPR acc, per-thread d2/din
// (no preamble barriers). Cross-block sums via two em half-buffers (summed in k3a)
// and an sx partial buffer combined in a k3b grid tail. k1/k3a/k3b/k4 otherwise
// unchanged from round 11 (passed, 1199us).

#define NB   32
#define NN   64
#define EPB  4096
#define HID  256
#define NL   9

typedef __attribute__((ext_vector_type(8))) short bfrag;   // 8 bf16 = 4 VGPRs
typedef __attribute__((ext_vector_type(4))) float f32x4;
typedef __attribute__((ext_vector_type(2))) float f32x2;

__device__ __forceinline__ float fast_rcp(float x) { return __builtin_amdgcn_rcpf(x); }
__device__ __forceinline__ float silu_f(float x) { return x * fast_rcp(1.f + __expf(-x)); }
__device__ __forceinline__ float sigm_f(float x) { return fast_rcp(1.f + __expf(-x)); }
__device__ __forceinline__ ushort bf16rne(float x) {
    unsigned u = __builtin_bit_cast(unsigned, x);
    u = (u + 0x7fffu + ((u >> 16) & 1u)) >> 16;
    return (ushort)u;
}
__device__ __forceinline__ float bf16tof(ushort h) {
    unsigned u = ((unsigned)h) << 16;
    return __builtin_bit_cast(float, u);
}
__device__ __forceinline__ unsigned pk2(f32x2 v) {
    float2 f; f.x = v.x; f.y = v.y;
    __hip_bfloat162 t = __float22bfloat162_rn(f);
    unsigned u;
    __builtin_memcpy(&u, &t, 4);
    return u;
}
__device__ __forceinline__ f32x2 fma2(f32x2 a, f32x2 b, f32x2 c) {
    return __builtin_elementwise_fma(a, b, c);
}
__device__ __forceinline__ f32x4 fma4(f32x4 a, f32x4 b, f32x4 c) {
    return __builtin_elementwise_fma(a, b, c);
}
__device__ __forceinline__ f32x2 silu2(f32x2 v) {
    f32x2 e = { __expf(-v.x), __expf(-v.y) };
    f32x2 d = e + (f32x2){1.f, 1.f};
    f32x2 r = { fast_rcp(d.x), fast_rcp(d.y) };
    return v * r;
}
__device__ __forceinline__ f32x4 silu4(f32x4 v) {
    f32x4 e = { __expf(-v.x), __expf(-v.y), __expf(-v.z), __expf(-v.w) };
    f32x4 d = e + (f32x4){1.f, 1.f, 1.f, 1.f};
    f32x4 r = { fast_rcp(d.x), fast_rcp(d.y), fast_rcp(d.z), fast_rcp(d.w) };
    return v * r;
}

// ---------------------------------------------------------------------------
// K0: h0 = [h_in, t] @ win_w + win_b ; d_in ; x copy
__global__ void edm_k0_pre(const float* __restrict__ x_in, const float* __restrict__ h_in,
                           const float* __restrict__ t_in,
                           const float* __restrict__ win_w, const float* __restrict__ win_b,
                           float* __restrict__ h0, float* __restrict__ din_ws,
                           float* __restrict__ x0)
{
    int blk = blockIdx.x, tid = threadIdx.x;
    if (blk < NB * NN) {
        int node = blk;
        float acc = win_b[tid];
        #pragma unroll
        for (int k = 0; k < 5; ++k) acc += h_in[node * 5 + k] * win_w[k * HID + tid];
        acc += t_in[node] * win_w[5 * HID + tid];
        h0[node * HID + tid] = acc;
    } else if (blk < NB * NN + 512) {
        int e = (blk - NB * NN) * 256 + tid;
        int b = e >> 12, r = e & 4095, i = r >> 6, j = r & 63;
        const float* xb = x_in + b * NN * 3;
        float d0 = xb[i*3+0] - xb[j*3+0];
        float d1 = xb[i*3+1] - xb[j*3+1];
        float d2 = xb[i*3+2] - xb[j*3+2];
        float ss = d0*d0 + d1*d1 + d2*d2;
        float d  = sqrtf(fmaxf(ss, 1e-12f));
        din_ws[e] = (i != j) ? d : 0.f;
    } else {
        int idx = (blk - (NB * NN + 512)) * 256 + tid;
        if (idx < NB * NN * 3) x0[idx] = x_in[idx];
    }
}

// ---------------------------------------------------------------------------
// K5: we_w2 / wx_w2 (fp32 [l][k][n]) -> bf16 transposed [l][n][k]
__global__ void edm_k5_prep(const float* __restrict__ we_w2, const float* __restrict__ wx_w2,
                            ushort* __restrict__ W2Te, ushort* __restrict__ W2Tx)
{
    __shared__ float t_s[64][65];
    int blk = blockIdx.x;
    int mat = blk / 144, rem = blk % 144, l = rem >> 4, tile = rem & 15;
    int kt = tile >> 2, nt = tile & 3;
    const float* src = (mat ? wx_w2 : we_w2) + l * HID * HID;
    ushort* dst = (mat ? W2Tx : W2Te) + l * HID * HID;
    int col = threadIdx.x & 63, rg = threadIdx.x >> 6;
    #pragma unroll
    for (int it = 0; it < 16; ++it) {
        int row = rg * 16 + it;
        t_s[row][col] = src[(kt * 64 + row) * HID + nt * 64 + col];
    }
    __syncthreads();
    #pragma unroll
    for (int it = 0; it < 16; ++it) {
        int n = rg * 16 + it;
        dst[(nt * 64 + n) * HID + kt * 64 + col] = bf16rne(t_s[col][n]);
    }
}

// ---------------------------------------------------------------------------
// K5b: we_w1/wx_w1 slices -> bf16 hi/lo transposed [l][out][n][k].
__global__ void edm_k5b_prep(const float* __restrict__ we_w1, const float* __restrict__ wx_w1,
                             ushort* __restrict__ W1Th, ushort* __restrict__ W1Tl)
{
    __shared__ float t_s[64][65];
    int blk = blockIdx.x;
    int tile = blk & 15, out = (blk >> 4) & 3, l = blk >> 6;
    int kt = tile >> 2, nt = tile & 3;
    const float* src = ((out >= 2) ? wx_w1 : we_w1) + l * 514 * HID + (out & 1) * 256 * HID;
    size_t doff = ((size_t)(l * 4 + out)) * HID * HID;
    ushort* dh = W1Th + doff;
    ushort* dl = W1Tl + doff;
    int col = threadIdx.x & 63, rg = threadIdx.x >> 6;
    #pragma unroll
    for (int it = 0; it < 16; ++it) {
        int row = rg * 16 + it;
        t_s[row][col] = src[(kt * 64 + row) * HID + nt * 64 + col];
    }
    __syncthreads();
    #pragma unroll
    for (int it = 0; it < 16; ++it) {
        int n = rg * 16 + it;
        float v = t_s[col][n];
        ushort h = bf16rne(v);
        float lo = v - bf16tof(h);
        dh[(nt * 64 + n) * HID + kt * 64 + col] = h;
        dl[(nt * 64 + n) * HID + kt * 64 + col] = bf16rne(lo);
    }
}

// ---------------------------------------------------------------------------
// K5c: wh_w1 -> W3h/W3l bf16 [l][n=256][k=512]; wh_w2 -> W4h/W4l bf16 [l][n][k].
__global__ void edm_k5c_prep(const float* __restrict__ wh_w1, const float* __restrict__ wh_w2,
                             ushort* __restrict__ W3h, ushort* __restrict__ W3l,
                             ushort* __restrict__ W4h, ushort* __restrict__ W4l)
{
    __shared__ float t_s[64][65];
    int blk = blockIdx.x;
    const float* src; ushort* dh; ushort* dl; int kt, nt, Kdim;
    if (blk < 288) {
        int l = blk >> 5, tile = blk & 31;
        kt = tile >> 2; nt = tile & 3; Kdim = 512;
        src = wh_w1 + (size_t)l * 512 * HID;
        dh = W3h + (size_t)l * HID * 512;
        dl = W3l + (size_t)l * HID * 512;
    } else {
        int b2 = blk - 288;
        int l = b2 >> 4, tile = b2 & 15;
        kt = tile >> 2; nt = tile & 3; Kdim = 256;
        src = wh_w2 + (size_t)l * HID * HID;
        dh = W4h + (size_t)l * HID * HID;
        dl = W4l + (size_t)l * HID * HID;
    }
    int col = threadIdx.x & 63, rg = threadIdx.x >> 6;
    #pragma unroll
    for (int it = 0; it < 16; ++it) {
        int row = rg * 16 + it;
        t_s[row][col] = src[(size_t)(kt * 64 + row) * HID + nt * 64 + col];
    }
    __syncthreads();
    #pragma unroll
    for (int it = 0; it < 16; ++it) {
        int n = rg * 16 + it;
        float v = t_s[col][n];
        ushort h = bf16rne(v);
        float lo = v - bf16tof(h);
        dh[(size_t)(nt * 64 + n) * Kdim + kt * 64 + col] = h;
        dl[(size_t)(nt * 64 + n) * Kdim + kt * 64 + col] = bf16rne(lo);
    }
}

// ---------------------------------------------------------------------------
// K1 (MFMA): HeA/HeB/HxA/HxB = h @ W1-slice (+bias) via bf16 hi/lo split.
__global__ __launch_bounds__(256)
void edm_k1_mfma(const float* __restrict__ h,
                 const ushort* __restrict__ W1Th, const ushort* __restrict__ W1Tl,
                 const float* __restrict__ we_b1, const float* __restrict__ wx_b1,
                 const float* __restrict__ we_w2, const float* __restrict__ we_b2,
                 const float* __restrict__ attn_w, const float* __restrict__ attn_b,
                 float* __restrict__ HeA, float* __restrict__ HeB,
                 float* __restrict__ HxA, float* __restrict__ HxB,
                 float* __restrict__ self_em, int l)
{
    int tid = threadIdx.x;
    if (blockIdx.x == 512) {
        __shared__ float m1s[HID];
        __shared__ float ms[HID];
        __shared__ float wred[4];
        __shared__ float gsh;
        const float* eb1 = we_b1 + l * HID;
        m1s[tid] = silu_f(eb1[tid]);
        __syncthreads();
        const float* W2 = we_w2 + l * HID * HID;
        float acc = we_b2[l * HID + tid];
        for (int k = 0; k < HID; ++k) acc += m1s[k] * W2[k * HID + tid];
        float mv = silu_f(acc);
        ms[tid] = mv;
        float p = mv * attn_w[l * HID + tid];
        #pragma unroll
        for (int off = 32; off > 0; off >>= 1) p += __shfl_down(p, off, 64);
        if ((tid & 63) == 0) wred[tid >> 6] = p;
        __syncthreads();
        if (tid == 0) gsh = sigm_f(wred[0] + wred[1] + wred[2] + wred[3] + attn_b[l]);
        __syncthreads();
        self_em[tid] = gsh * ms[tid];
        return;
    }

    __shared__ __align__(16) ushort Ah_s[16384];
    __shared__ __align__(16) ushort Al_s[16384];

    const int cq = blockIdx.x & 3;
    const int out = (blockIdx.x >> 2) & 3;
    const int ntile = blockIdx.x >> 4;
    const int base = ntile * 64;

    {
        const int c  = tid & 31;
        const int jg = tid >> 5;
        const int k0 = c * 8;
        #pragma unroll
        for (int it = 0; it < 8; ++it) {
            int m = it * 8 + jg;
            f32x4 h0 = *(const f32x4*)&h[(base + m) * HID + k0];
            f32x4 h1 = *(const f32x4*)&h[(base + m) * HID + k0 + 4];
            uint4 phi, plo;
            {
                ushort ax = bf16rne(h0.x), ay = bf16rne(h0.y);
                phi.x = (unsigned)ax | ((unsigned)ay << 16);
                plo.x = pk2((f32x2){h0.x - bf16tof(ax), h0.y - bf16tof(ay)});
            }
            {
                ushort ax = bf16rne(h0.z), ay = bf16rne(h0.w);
                phi.y = (unsigned)ax | ((unsigned)ay << 16);
                plo.y = pk2((f32x2){h0.z - bf16tof(ax), h0.w - bf16tof(ay)});
            }
            {
                ushort ax = bf16rne(h1.x), ay = bf16rne(h1.y);
                phi.z = (unsigned)ax | ((unsigned)ay << 16);
                plo.z = pk2((f32x2){h1.x - bf16tof(ax), h1.y - bf16tof(ay)});
            }
            {
                ushort ax = bf16rne(h1.z), ay = bf16rne(h1.w);
                phi.w = (unsigned)ax | ((unsigned)ay << 16);
                plo.w = pk2((f32x2){h1.z - bf16tof(ax), h1.w - bf16tof(ay)});
            }
            unsigned off = (unsigned)(m * 256 + ((c ^ (m & 7)) * 8));
            *(uint4*)&Ah_s[off] = phi;
            *(uint4*)&Al_s[off] = plo;
        }
    }
    __syncthreads();

    const int w = tid >> 6, lane = tid & 63, quad = lane >> 4, l16 = lane & 15;
    const int col = cq * 64 + w * 16 + l16;
    const ushort* Bh = W1Th + ((size_t)(l * 4 + out)) * HID * HID + (size_t)col * HID;
    const ushort* Bl = W1Tl + ((size_t)(l * 4 + out)) * HID * HID + (size_t)col * HID;

    f32x4 acc[4];
    #pragma unroll
    for (int mt = 0; mt < 4; ++mt) acc[mt] = (f32x4){0.f, 0.f, 0.f, 0.f};

    #pragma unroll
    for (int kt = 0; kt < 8; ++kt) {
        const int kof = kt * 32 + quad * 8;
        const int ch  = (kt * 4 + quad) ^ (l16 & 7);
        bfrag bh = *(const bfrag*)&Bh[kof];
        bfrag bl = *(const bfrag*)&Bl[kof];
        bfrag ahr[4], alr[4];
        #pragma unroll
        for (int mt = 0; mt < 4; ++mt) {
            ahr[mt] = *(const bfrag*)&Ah_s[(mt * 16 + l16) * 256 + ch * 8];
            alr[mt] = *(const bfrag*)&Al_s[(mt * 16 + l16) * 256 + ch * 8];
        }
        #pragma unroll
        for (int mt = 0; mt < 4; ++mt) {
            acc[mt] = __builtin_amdgcn_mfma_f32_16x16x32_bf16(ahr[mt], bh, acc[mt], 0, 0, 0);
            acc[mt] = __builtin_amdgcn_mfma_f32_16x16x32_bf16(ahr[mt], bl, acc[mt], 0, 0, 0);
            acc[mt] = __builtin_amdgcn_mfma_f32_16x16x32_bf16(alr[mt], bh, acc[mt], 0, 0, 0);
        }
    }

    float bias = 0.f;
    if (out == 0) bias = we_b1[l * HID + col];
    else if (out == 2) bias = wx_b1[l * HID + col];
    float* dst = (out == 0) ? HeA : (out == 1) ? HeB : (out == 2) ? HxA : HxB;
    #pragma unroll
    for (int mt = 0; mt < 4; ++mt)
        #pragma unroll
        for (int r = 0; r < 4; ++r)
            dst[(base + mt * 16 + quad * 4 + r) * HID + col] = acc[mt][r] + bias;
}

// ---------------------------------------------------------------------------
// KB: m-half edge kernel. grid 8192: p = blk>>12, bi = (blk&4095)>>1, mh = blk&1.
// Block computes rows [mh*32, mh*32+32) x 256 cols. Phase A barrier-free
// (per-thread d2/din from broadcast L2 loads). em partials -> emg[mh] half-buffers
// (summed in k3a); p1 coordinate partials -> sx[mh][bi] (combined in k3b tail).
__global__ __launch_bounds__(256, 4)
void edm_kb_gemm(const float* __restrict__ x_cur,
                 const float* __restrict__ HeA, const float* __restrict__ HeB,
                 const float* __restrict__ HxA, const float* __restrict__ HxB,
                 const float* __restrict__ din_ws,
                 const float* __restrict__ we_w1, const float* __restrict__ we_b1,
                 const float* __restrict__ wx_w1, const float* __restrict__ wx_b1,
                 const ushort* __restrict__ W2Te, const ushort* __restrict__ W2Tx,
                 const float* __restrict__ we_b2, const float* __restrict__ wx_b2,
                 const float* __restrict__ attn_w, const float* __restrict__ attn_b,
                 const float* __restrict__ wx_w3,
                 float* __restrict__ emg, float* __restrict__ sx, int l)
{
    __shared__ __align__(16) ushort A_s[32 * 256];   // 16 KB
    __shared__ float red_s[128];
    __shared__ float sc_s[32];
    __shared__ float x_s[192];

    const int tid = threadIdx.x;
    const int blk = blockIdx.x;
    const int p = blk >> 12, rem = blk & 4095, bi = rem >> 1, mh = rem & 1;
    const int b = bi >> 6, i = bi & 63;
    const size_t SN = (size_t)NB * NN * HID;

    if (tid < 192) x_s[tid] = x_cur[b * 192 + tid];   // consumed after GEMM barrier

    // ---------------- phase A (barrier-free): rows mh*32 .. mh*32+31 ----------
    {
        const float* W1  = (p ? wx_w1 : we_w1) + l * 514 * HID;
        const float* HA  = (p ? HxA : HeA);
        const float* HB  = (p ? HxB : HeB);
        const float* b1p = (p ? wx_b1 : we_b1) + l * HID;

        const int c  = tid & 31;
        const int jg = tid >> 5;          // 0..7 -> 4 rows per thread
        const int k0 = c * 8;

        float xi0 = x_cur[b * 192 + i * 3 + 0];
        float xi1 = x_cur[b * 192 + i * 3 + 1];
        float xi2 = x_cur[b * 192 + i * 3 + 2];

        f32x4 ra0 = *(const f32x4*)&HA[(b * 64 + i) * HID + k0];
        f32x4 ra1 = *(const f32x4*)&HA[(b * 64 + i) * HID + k0 + 4];
        f32x4 wa0 = *(const f32x4*)&W1[512 * HID + k0];
        f32x4 wa1 = *(const f32x4*)&W1[512 * HID + k0 + 4];
        f32x4 wb0 = *(const f32x4*)&W1[513 * HID + k0];
        f32x4 wb1 = *(const f32x4*)&W1[513 * HID + k0 + 4];
        f32x4 b10 = *(const f32x4*)&b1p[k0];
        f32x4 b11 = *(const f32x4*)&b1p[k0 + 4];
        uint4 pki;                         // self-edge row: silu(b1)
        pki.x = pk2(silu2((f32x2){b10.x, b10.y}));
        pki.y = pk2(silu2((f32x2){b10.z, b10.w}));
        pki.z = pk2(silu2((f32x2){b11.x, b11.y}));
        pki.w = pk2(silu2((f32x2){b11.z, b11.w}));

        const float* hbp = HB + b * 64 * HID + k0;
        #pragma unroll
        for (int it = 0; it < 4; ++it) {
            int lj = it * 8 + jg;          // local row 0..31
            int j  = mh * 32 + lj;         // global row
            float xj0 = x_cur[b * 192 + j * 3 + 0];
            float xj1 = x_cur[b * 192 + j * 3 + 1];
            float xj2 = x_cur[b * 192 + j * 3 + 2];
            float e0 = xi0 - xj0, e1 = xi1 - xj1, e2 = xi2 - xj2;
            float ss = e0*e0 + e1*e1 + e2*e2;
            float d  = sqrtf(fmaxf(ss, 1e-12f));
            float d2v = d * d;
            float dnv = din_ws[b * EPB + i * 64 + j];

            f32x4 h0 = *(const f32x4*)&hbp[j * HID];
            f32x4 h1 = *(const f32x4*)&hbp[j * HID + 4];
            f32x2 dd = { d2v, d2v };
            f32x2 dn = { dnv, dnv };
            uint4 pkv;
            f32x2 v;
            v = fma2(dn, (f32x2){wb0.x, wb0.y},
                 fma2(dd, (f32x2){wa0.x, wa0.y},
                      (f32x2){ra0.x + h0.x, ra0.y + h0.y}));
            pkv.x = pk2(silu2(v));
            v = fma2(dn, (f32x2){wb0.z, wb0.w},
                 fma2(dd, (f32x2){wa0.z, wa0.w},
                      (f32x2){ra0.z + h0.z, ra0.w + h0.w}));
            pkv.y = pk2(silu2(v));
            v = fma2(dn, (f32x2){wb1.x, wb1.y},
                 fma2(dd, (f32x2){wa1.x, wa1.y},
                      (f32x2){ra1.x + h1.x, ra1.y + h1.y}));
            pkv.z = pk2(silu2(v));
            v = fma2(dn, (f32x2){wb1.z, wb1.w},
                 fma2(dd, (f32x2){wa1.z, wa1.w},
                      (f32x2){ra1.z + h1.z, ra1.w + h1.w}));
            pkv.w = pk2(silu2(v));
            if (j == i) pkv = pki;
            *(uint4*)&A_s[lj * 256 + (unsigned)((c ^ (lj & 7)) * 8)] = pkv;
        }
    }
    __syncthreads();

    // ---------------- GEMM: 32 x 256 = A(32x256) @ W2(256x256) ----------------
    const int w = tid >> 6, lane = tid & 63, quad = lane >> 4, l16 = lane & 15;
    const ushort* W2T = (p ? W2Tx : W2Te) + l * HID * HID;
    const int cb0 = w * 64 + l16;
    f32x4 acc[2][4];
    #pragma unroll
    for (int mt = 0; mt < 2; ++mt)
        #pragma unroll
        for (int nt = 0; nt < 4; ++nt) acc[mt][nt] = (f32x4){0.f, 0.f, 0.f, 0.f};

    #pragma unroll
    for (int kt = 0; kt < 8; ++kt) {
        const int kof = kt * 32 + quad * 8;
        const int ch  = (kt * 4 + quad) ^ (l16 & 7);
        bfrag bfr[4], afr[2];
        #pragma unroll
        for (int nt = 0; nt < 4; ++nt)
            bfr[nt] = *(const bfrag*)&W2T[(cb0 + nt * 16) * HID + kof];
        #pragma unroll
        for (int mt = 0; mt < 2; ++mt)
            afr[mt] = *(const bfrag*)&A_s[(mt * 16 + l16) * 256 + ch * 8];
        #pragma unroll
        for (int mt = 0; mt < 2; ++mt)
            #pragma unroll
            for (int nt = 0; nt < 4; ++nt)
                acc[mt][nt] = __builtin_amdgcn_mfma_f32_16x16x32_bf16(
                    afr[mt], bfr[nt], acc[mt][nt], 0, 0, 0);
    }

    // ---------------- epilogue ----------------
    const float* b2p = (p ? wx_b2 : we_b2) + l * HID;
    const float* vvp = p ? (wx_w3 + l * HID) : (attn_w + l * HID);
    float b2v[4], vv[4];
    #pragma unroll
    for (int nt = 0; nt < 4; ++nt) { b2v[nt] = b2p[cb0 + nt * 16]; vv[nt] = vvp[cb0 + nt * 16]; }

    #pragma unroll
    for (int mt = 0; mt < 2; ++mt)
        #pragma unroll
        for (int nt = 0; nt < 4; ++nt) {
            f32x4 bb = { b2v[nt], b2v[nt], b2v[nt], b2v[nt] };
            acc[mt][nt] = silu4(acc[mt][nt] + bb);
        }

    #pragma unroll
    for (int mt = 0; mt < 2; ++mt) {
        f32x4 t4 = acc[mt][0] * (f32x4){vv[0], vv[0], vv[0], vv[0]};
        t4 = fma4(acc[mt][1], (f32x4){vv[1], vv[1], vv[1], vv[1]}, t4);
        t4 = fma4(acc[mt][2], (f32x4){vv[2], vv[2], vv[2], vv[2]}, t4);
        t4 = fma4(acc[mt][3], (f32x4){vv[3], vv[3], vv[3], vv[3]}, t4);
        #pragma unroll
        for (int r = 0; r < 4; ++r) {
            float pd = t4[r];
            pd += __shfl_xor(pd, 1, 64); pd += __shfl_xor(pd, 2, 64);
            pd += __shfl_xor(pd, 4, 64); pd += __shfl_xor(pd, 8, 64);
            if (l16 == 0) red_s[w * 32 + mt * 16 + quad * 4 + r] = pd;
        }
    }
    __syncthreads();
    if (tid < 32) {
        float tot = red_s[tid] + red_s[32 + tid] + red_s[64 + tid] + red_s[96 + tid];
        int j = mh * 32 + tid;
        if (p == 0) sc_s[tid] = (j == i) ? 0.f : sigm_f(tot + attn_b[l]);
        else        sc_s[tid] = tot;
    }
    __syncthreads();

    if (p == 0) {
        f32x4 g[2];
        #pragma unroll
        for (int mt = 0; mt < 2; ++mt) g[mt] = *(const f32x4*)&sc_s[mt * 16 + quad * 4];
        #pragma unroll
        for (int nt = 0; nt < 4; ++nt) {
            f32x4 e4 = g[0] * acc[0][nt];
            e4 = fma4(g[1], acc[1][nt], e4);
            float e = (e4.x + e4.y) + (e4.z + e4.w);
            e += __shfl_xor(e, 16, 64); e += __shfl_xor(e, 32, 64);
            if (quad == 0)
                emg[mh * SN + (size_t)(b * 64 + i) * HID + cb0 + nt * 16] = e;
        }
    } else {
        if (tid < 32) {
            int j = mh * 32 + tid;
            float d0 = x_s[i*3+0] - x_s[j*3+0];
            float d1 = x_s[i*3+1] - x_s[j*3+1];
            float d2 = x_s[i*3+2] - x_s[j*3+2];
            float ss = d0*d0 + d1*d1 + d2*d2;
            float d  = sqrtf(fmaxf(ss, 1e-12f));
            float f  = fast_rcp(d + 1.f) * sc_s[tid];
            float cx = d0 * f, cy = d1 * f, cz = d2 * f;
            #pragma unroll
            for (int off = 16; off > 0; off >>= 1) {
                cx += __shfl_down(cx, off, 64);
                cy += __shfl_down(cy, off, 64);
                cz += __shfl_down(cz, off, 64);
            }
            if (tid == 0) {
                float* sxp = sx + (size_t)(mh * 2048 + bi) * 4;
                sxp[0] = cx; sxp[1] = cy; sxp[2] = cz;
            }
        }
    }
}

// ---------------------------------------------------------------------------
// K3a: u = silu(cat @ wh_w1 + b1), cat = [h | emg0+emg1+self_em] (2048x512).
// grid 512; writes u hi/lo bf16 swizzled to global for k3b.
__global__ __launch_bounds__(256)
void edm_k3a(const float* __restrict__ h, const float* __restrict__ emg,
             const float* __restrict__ self_em,
             const ushort* __restrict__ W3h, const ushort* __restrict__ W3l,
             const float* __restrict__ wh_b1,
             ushort* __restrict__ Uh, ushort* __restrict__ Ul, int l)
{
    __shared__ __align__(16) ushort Ah_s[16 * 512];
    __shared__ __align__(16) ushort Al_s[16 * 512];

    const int tid = threadIdx.x;
    const int cq = blockIdx.x & 3;
    const int base = (blockIdx.x >> 2) * 16;
    const size_t SN = (size_t)NB * NN * HID;

    {
        const int c  = tid & 63;
        const int jg = tid >> 6;
        const int k0 = c * 8;
        #pragma unroll
        for (int t = 0; t < 4; ++t) {
            int m = t * 4 + jg;
            f32x4 v0, v1;
            if (c < 32) {
                v0 = *(const f32x4*)&h[(base + m) * HID + k0];
                v1 = *(const f32x4*)&h[(base + m) * HID + k0 + 4];
            } else {
                int e0 = k0 - 256;
                f32x4 a0 = *(const f32x4*)&emg[(size_t)(base + m) * HID + e0];
                f32x4 a1 = *(const f32x4*)&emg[(size_t)(base + m) * HID + e0 + 4];
                f32x4 c0 = *(const f32x4*)&emg[SN + (size_t)(base + m) * HID + e0];
                f32x4 c1 = *(const f32x4*)&emg[SN + (size_t)(base + m) * HID + e0 + 4];
                f32x4 s0 = *(const f32x4*)&self_em[e0];
                f32x4 s1 = *(const f32x4*)&self_em[e0 + 4];
                v0 = (a0 + c0) + s0; v1 = (a1 + c1) + s1;
            }
            uint4 phi, plo;
            {
                ushort ax = bf16rne(v0.x), ay = bf16rne(v0.y);
                phi.x = (unsigned)ax | ((unsigned)ay << 16);
                plo.x = pk2((f32x2){v0.x - bf16tof(ax), v0.y - bf16tof(ay)});
            }
            {
                ushort ax = bf16rne(v0.z), ay = bf16rne(v0.w);
                phi.y = (unsigned)ax | ((unsigned)ay << 16);
                plo.y = pk2((f32x2){v0.z - bf16tof(ax), v0.w - bf16tof(ay)});
            }
            {
                ushort ax = bf16rne(v1.x), ay = bf16rne(v1.y);
                phi.z = (unsigned)ax | ((unsigned)ay << 16);
                plo.z = pk2((f32x2){v1.x - bf16tof(ax), v1.y - bf16tof(ay)});
            }
            {
                ushort ax = bf16rne(v1.z), ay = bf16rne(v1.w);
                phi.w = (unsigned)ax | ((unsigned)ay << 16);
                plo.w = pk2((f32x2){v1.z - bf16tof(ax), v1.w - bf16tof(ay)});
            }
            unsigned off = (unsigned)(m * 512 + ((c ^ (m & 7)) * 8));
            *(uint4*)&Ah_s[off] = phi;
            *(uint4*)&Al_s[off] = plo;
        }
    }
    __syncthreads();

    const int w = tid >> 6, lane = tid & 63, quad = lane >> 4, l16 = lane & 15;
    const int colv = cq * 64 + w * 16 + l16;

    f32x4 acc = (f32x4){0.f, 0.f, 0.f, 0.f};
    const ushort* Bh = W3h + ((size_t)l * HID + colv) * 512;
    const ushort* Bl = W3l + ((size_t)l * HID + colv) * 512;

    for (int ks = 0; ks < 16; ++ks) {
        const int kof = ks * 32 + quad * 8;
        unsigned aoff = (unsigned)(l16 * 512 + (((ks * 4 + quad) ^ (l16 & 7))) * 8);
        bfrag ah = *(const bfrag*)&Ah_s[aoff];
        bfrag al = *(const bfrag*)&Al_s[aoff];
        bfrag bh = *(const bfrag*)&Bh[kof];
        bfrag bl = *(const bfrag*)&Bl[kof];
        acc = __builtin_amdgcn_mfma_f32_16x16x32_bf16(ah, bh, acc, 0, 0, 0);
        acc = __builtin_amdgcn_mfma_f32_16x16x32_bf16(ah, bl, acc, 0, 0, 0);
        acc = __builtin_amdgcn_mfma_f32_16x16x32_bf16(al, bh, acc, 0, 0, 0);
    }

    float b1v = wh_b1[l * HID + colv];
    #pragma unroll
    for (int r = 0; r < 4; ++r) {
        float u = silu_f(acc[r] + b1v);
        ushort uh = bf16rne(u);
        float ulo = u - bf16tof(uh);
        int row = quad * 4 + r;
        size_t ao = (size_t)(base + row) * 256 + (((colv >> 3) ^ (row & 7))) * 8 + (colv & 7);
        Uh[ao] = uh;
        Ul[ao] = bf16rne(ulo);
    }
}

// ---------------------------------------------------------------------------
// K3b: h_next = h + u @ wh_w2 + b2 (grid 512) + tail blocks 512..519:
// x_next = x_cur + sx0 + sx1 (combines KB p1 partials).
__global__ __launch_bounds__(256)
void edm_k3b(const float* __restrict__ h,
             const ushort* __restrict__ Uh, const ushort* __restrict__ Ul,
             const ushort* __restrict__ W4h, const ushort* __restrict__ W4l,
             const float* __restrict__ wh_b2,
             float* __restrict__ h_next,
             const float* __restrict__ x_cur, const float* __restrict__ sx,
             float* __restrict__ x_next, int l)
{
    const int tid = threadIdx.x;
    if (blockIdx.x >= 512) {
        int t = blockIdx.x - 512;            // 0..7
        #pragma unroll
        for (int s = 0; s < 3; ++s) {
            int f = t * 768 + s * 256 + tid; // 0..6143
            int node = f / 3, comp = f - node * 3;
            x_next[f] = x_cur[f] + sx[(size_t)node * 4 + comp]
                                 + sx[(size_t)(2048 + node) * 4 + comp];
        }
        return;
    }

    const int cq = blockIdx.x & 3;
    const int base = (blockIdx.x >> 2) * 16;
    const int w = tid >> 6, lane = tid & 63, quad = lane >> 4, l16 = lane & 15;
    const int colv = cq * 64 + w * 16 + l16;

    const ushort* Bh = W4h + ((size_t)l * HID + colv) * HID;
    const ushort* Bl = W4l + ((size_t)l * HID + colv) * HID;
    const ushort* Ah = Uh + (size_t)(base + l16) * 256;
    const ushort* Al = Ul + (size_t)(base + l16) * 256;

    f32x4 acc = (f32x4){0.f, 0.f, 0.f, 0.f};
    #pragma unroll
    for (int kt = 0; kt < 8; ++kt) {
        const int kof = kt * 32 + quad * 8;
        unsigned ach = (unsigned)((((kt * 4 + quad) ^ (l16 & 7))) * 8);
        bfrag ah = *(const bfrag*)&Ah[ach];
        bfrag al = *(const bfrag*)&Al[ach];
        bfrag bh = *(const bfrag*)&Bh[kof];
        bfrag bl = *(const bfrag*)&Bl[kof];
        acc = __builtin_amdgcn_mfma_f32_16x16x32_bf16(ah, bh, acc, 0, 0, 0);
        acc = __builtin_amdgcn_mfma_f32_16x16x32_bf16(ah, bl, acc, 0, 0, 0);
        acc = __builtin_amdgcn_mfma_f32_16x16x32_bf16(al, bh, acc, 0, 0, 0);
    }

    float b2v = wh_b2[l * HID + colv];
    #pragma unroll
    for (int r = 0; r < 4; ++r) {
        int node = base + quad * 4 + r;
        h_next[node * HID + colv] = h[node * HID + colv] + acc[r] + b2v;
    }
}

// ---------------------------------------------------------------------------
// K4: x_out = remove_mean(x - x_in); h_out = (h@wout_w + wout_b)[:, :5]
__global__ void edm_k4_out(const float* __restrict__ x_fin, const float* __restrict__ x_in,
                           const float* __restrict__ h_fin,
                           const float* __restrict__ wout_w, const float* __restrict__ wout_b,
                           float* __restrict__ out)
{
    __shared__ float vx[192];
    __shared__ float mean_s[3];
    int b = blockIdx.x, tid = threadIdx.x;
    if (tid < 192) vx[tid] = x_fin[b * 192 + tid] - x_in[b * 192 + tid];
    __syncthreads();
    if (tid < 3) {
        float s = 0.f;
        for (int n = 0; n < 64; ++n) s += vx[n * 3 + tid];
        mean_s[tid] = s * (1.f / 64.f);
    }
    __syncthreads();
    if (tid < 192) out[b * 512 + (tid / 3) * 8 + (tid % 3)] = vx[tid] - mean_s[tid % 3];

    int node = tid / 5, ch = tid % 5;
    float acc = wout_b[ch];
    const float* hr = h_fin + (b * 64 + node) * HID;
    for (int k = 0; k < HID; ++k) acc = fmaf(hr[k], wout_w[k * 6 + ch], acc);
    out[b * 512 + node * 8 + 3 + ch] = acc;
}

// ---------------------------------------------------------------------------
extern "C" void kernel_launch(void* const* d_in, const int* in_sizes, int n_in,
                              void* d_out, int out_size, void* d_ws, size_t ws_size,
                              hipStream_t stream)
{
    const float* x_in   = (const float*)d_in[0];
    const float* h_in   = (const float*)d_in[1];
    const float* t_in   = (const float*)d_in[2];
    const float* win_w  = (const float*)d_in[6];
    const float* win_b  = (const float*)d_in[7];
    const float* wout_w = (const float*)d_in[8];
    const float* wout_b = (const float*)d_in[9];
    const float* we_w1  = (const float*)d_in[10];
    const float* we_b1  = (const float*)d_in[11];
    const float* we_w2  = (const float*)d_in[12];
    const float* we_b2  = (const float*)d_in[13];
    const float* attn_w = (const float*)d_in[14];
    const float* attn_b = (const float*)d_in[15];
    const float* wh_w1  = (const float*)d_in[16];
    const float* wh_b1  = (const float*)d_in[17];
    const float* wh_w2  = (const float*)d_in[18];
    const float* wh_b2  = (const float*)d_in[19];
    const float* wx_w1  = (const float*)d_in[20];
    const float* wx_b1  = (const float*)d_in[21];
    const float* wx_w2  = (const float*)d_in[22];
    const float* wx_b2  = (const float*)d_in[23];
    const float* wx_w3  = (const float*)d_in[24];

    float* ws = (float*)d_ws;
    const size_t SN = (size_t)NB * NN * HID;     // 524288
    float* h_a = ws;
    float* h_b = ws + SN;
    float* HeA = ws + 2 * SN;
    float* HeB = ws + 3 * SN;
    float* HxA = ws + 4 * SN;
    float* HxB = ws + 5 * SN;
    float* emg = ws + 6 * SN;                    // 2*SN (two m-halves)
    float* din = ws + 8 * SN;
    float* x_a = din + (size_t)NB * EPB;
    float* x_b = x_a + NB * NN * 3;
    float* sem = x_b + NB * NN * 3;
    float* sx  = sem + 256;                      // 2*2048*4 floats
    ushort* W2Te = (ushort*)(sx + 2 * 2048 * 4);
    ushort* W2Tx = W2Te + (size_t)NL * HID * HID;
    ushort* W1Th = W2Tx + (size_t)NL * HID * HID;
    ushort* W1Tl = W1Th + (size_t)NL * 4 * HID * HID;
    ushort* W3h  = W1Tl + (size_t)NL * 4 * HID * HID;
    ushort* W3l  = W3h + (size_t)NL * HID * 512;
    ushort* W4h  = W3l + (size_t)NL * HID * 512;
    ushort* W4l  = W4h + (size_t)NL * HID * HID;
    ushort* Uh   = W4l + (size_t)NL * HID * HID;
    ushort* Ul   = Uh + (size_t)NB * NN * HID;
    // total ws ~37 MB

    edm_k5_prep<<<dim3(288), dim3(256), 0, stream>>>(we_w2, wx_w2, W2Te, W2Tx);
    edm_k5b_prep<<<dim3(576), dim3(256), 0, stream>>>(we_w1, wx_w1, W1Th, W1Tl);
    edm_k5c_prep<<<dim3(432), dim3(256), 0, stream>>>(wh_w1, wh_w2, W3h, W3l, W4h, W4l);

    edm_k0_pre<<<dim3(NB * NN + 512 + 24), dim3(256), 0, stream>>>(
        x_in, h_in, t_in, win_w, win_b, h_a, din, x_a);

    for (int l = 0; l < NL; ++l) {
        float* h_cur = (l & 1) ? h_b : h_a;
        float* h_nxt = (l & 1) ? h_a : h_b;
        float* x_cur = (l & 1) ? x_b : x_a;
        float* x_nxt = (l & 1) ? x_a : x_b;

        edm_k1_mfma<<<dim3(513), dim3(256), 0, stream>>>(
            h_cur, W1Th, W1Tl, we_b1, wx_b1, we_w2, we_b2, attn_w, attn_b,
            HeA, HeB, HxA, HxB, sem, l);

        edm_kb_gemm<<<dim3(2 * 4096), dim3(256), 0, stream>>>(
            x_cur, HeA, HeB, HxA, HxB, din,
            we_w1, we_b1, wx_w1, wx_b1, W2Te, W2Tx,
            we_b2, wx_b2, attn_w, attn_b, wx_w3, emg, sx, l);

        edm_k3a<<<dim3(512), dim3(256), 0, stream>>>(
            h_cur, emg, sem, W3h, W3l, wh_b1, Uh, Ul, l);

        edm_k3b<<<dim3(520), dim3(256), 0, stream>>>(
            h_cur, Uh, Ul, W4h, W4l, wh_b2, h_nxt, x_cur, sx, x_nxt, l);
    }

    edm_k4_out<<<dim3(NB), dim3(320), 0, stream>>>(
        x_b, x_in, h_b, wout_w, wout_b, (float*)d_out);
}

// Round 13
// 1189.522 us; speedup vs baseline: 1.4628x; 1.4628x over previous
//
#include <hip/hip_runtime.h>
#include <hip/hip_bf16.h>
#include <math.h>

// EquivariantDiffusionModel on MI355X — round 13 (= round 11 + KB XCD-locality fix).
// Round 12's m-half split regressed (per-block overhead + doubled B-loads, no
// occupancy gain) -> reverted. KB changes vs round 11:
//   (1) block->(b,i) remap: i in HIGH bits (i=rem>>5, b=rem&31) so all 64 blocks
//       of a batch b share blk%8 -> land on one XCD -> HeB tile fetched into one
//       L2 instead of all 8 (FETCH was 19.9MB ~= 8x input set).
//   (2) preamble: x_s staging + d2/din computed under a single barrier (was 2).

#define NB   32
#define NN   64
#define EPB  4096
#define HID  256
#define NL   9

typedef __attribute__((ext_vector_type(8))) short bfrag;   // 8 bf16 = 4 VGPRs
typedef __attribute__((ext_vector_type(4))) float f32x4;
typedef __attribute__((ext_vector_type(2))) float f32x2;

__device__ __forceinline__ float fast_rcp(float x) { return __builtin_amdgcn_rcpf(x); }
__device__ __forceinline__ float silu_f(float x) { return x * fast_rcp(1.f + __expf(-x)); }
__device__ __forceinline__ float sigm_f(float x) { return fast_rcp(1.f + __expf(-x)); }
__device__ __forceinline__ ushort bf16rne(float x) {
    unsigned u = __builtin_bit_cast(unsigned, x);
    u = (u + 0x7fffu + ((u >> 16) & 1u)) >> 16;
    return (ushort)u;
}
__device__ __forceinline__ float bf16tof(ushort h) {
    unsigned u = ((unsigned)h) << 16;
    return __builtin_bit_cast(float, u);
}
__device__ __forceinline__ unsigned pk2(f32x2 v) {
    float2 f; f.x = v.x; f.y = v.y;
    __hip_bfloat162 t = __float22bfloat162_rn(f);
    unsigned u;
    __builtin_memcpy(&u, &t, 4);
    return u;
}
__device__ __forceinline__ f32x2 fma2(f32x2 a, f32x2 b, f32x2 c) {
    return __builtin_elementwise_fma(a, b, c);
}
__device__ __forceinline__ f32x4 fma4(f32x4 a, f32x4 b, f32x4 c) {
    return __builtin_elementwise_fma(a, b, c);
}
__device__ __forceinline__ f32x2 silu2(f32x2 v) {
    f32x2 e = { __expf(-v.x), __expf(-v.y) };
    f32x2 d = e + (f32x2){1.f, 1.f};
    f32x2 r = { fast_rcp(d.x), fast_rcp(d.y) };
    return v * r;
}
__device__ __forceinline__ f32x4 silu4(f32x4 v) {
    f32x4 e = { __expf(-v.x), __expf(-v.y), __expf(-v.z), __expf(-v.w) };
    f32x4 d = e + (f32x4){1.f, 1.f, 1.f, 1.f};
    f32x4 r = { fast_rcp(d.x), fast_rcp(d.y), fast_rcp(d.z), fast_rcp(d.w) };
    return v * r;
}

// ---------------------------------------------------------------------------
// K0: h0 = [h_in, t] @ win_w + win_b ; d_in ; x copy
__global__ void edm_k0_pre(const float* __restrict__ x_in, const float* __restrict__ h_in,
                           const float* __restrict__ t_in,
                           const float* __restrict__ win_w, const float* __restrict__ win_b,
                           float* __restrict__ h0, float* __restrict__ din_ws,
                           float* __restrict__ x0)
{
    int blk = blockIdx.x, tid = threadIdx.x;
    if (blk < NB * NN) {
        int node = blk;
        float acc = win_b[tid];
        #pragma unroll
        for (int k = 0; k < 5; ++k) acc += h_in[node * 5 + k] * win_w[k * HID + tid];
        acc += t_in[node] * win_w[5 * HID + tid];
        h0[node * HID + tid] = acc;
    } else if (blk < NB * NN + 512) {
        int e = (blk - NB * NN) * 256 + tid;
        int b = e >> 12, r = e & 4095, i = r >> 6, j = r & 63;
        const float* xb = x_in + b * NN * 3;
        float d0 = xb[i*3+0] - xb[j*3+0];
        float d1 = xb[i*3+1] - xb[j*3+1];
        float d2 = xb[i*3+2] - xb[j*3+2];
        float ss = d0*d0 + d1*d1 + d2*d2;
        float d  = sqrtf(fmaxf(ss, 1e-12f));
        din_ws[e] = (i != j) ? d : 0.f;
    } else {
        int idx = (blk - (NB * NN + 512)) * 256 + tid;
        if (idx < NB * NN * 3) x0[idx] = x_in[idx];
    }
}

// ---------------------------------------------------------------------------
// K5: we_w2 / wx_w2 (fp32 [l][k][n]) -> bf16 transposed [l][n][k]
__global__ void edm_k5_prep(const float* __restrict__ we_w2, const float* __restrict__ wx_w2,
                            ushort* __restrict__ W2Te, ushort* __restrict__ W2Tx)
{
    __shared__ float t_s[64][65];
    int blk = blockIdx.x;
    int mat = blk / 144, rem = blk % 144, l = rem >> 4, tile = rem & 15;
    int kt = tile >> 2, nt = tile & 3;
    const float* src = (mat ? wx_w2 : we_w2) + l * HID * HID;
    ushort* dst = (mat ? W2Tx : W2Te) + l * HID * HID;
    int col = threadIdx.x & 63, rg = threadIdx.x >> 6;
    #pragma unroll
    for (int it = 0; it < 16; ++it) {
        int row = rg * 16 + it;
        t_s[row][col] = src[(kt * 64 + row) * HID + nt * 64 + col];
    }
    __syncthreads();
    #pragma unroll
    for (int it = 0; it < 16; ++it) {
        int n = rg * 16 + it;
        dst[(nt * 64 + n) * HID + kt * 64 + col] = bf16rne(t_s[col][n]);
    }
}

// ---------------------------------------------------------------------------
// K5b: we_w1/wx_w1 slices -> bf16 hi/lo transposed [l][out][n][k].
__global__ void edm_k5b_prep(const float* __restrict__ we_w1, const float* __restrict__ wx_w1,
                             ushort* __restrict__ W1Th, ushort* __restrict__ W1Tl)
{
    __shared__ float t_s[64][65];
    int blk = blockIdx.x;
    int tile = blk & 15, out = (blk >> 4) & 3, l = blk >> 6;
    int kt = tile >> 2, nt = tile & 3;
    const float* src = ((out >= 2) ? wx_w1 : we_w1) + l * 514 * HID + (out & 1) * 256 * HID;
    size_t doff = ((size_t)(l * 4 + out)) * HID * HID;
    ushort* dh = W1Th + doff;
    ushort* dl = W1Tl + doff;
    int col = threadIdx.x & 63, rg = threadIdx.x >> 6;
    #pragma unroll
    for (int it = 0; it < 16; ++it) {
        int row = rg * 16 + it;
        t_s[row][col] = src[(kt * 64 + row) * HID + nt * 64 + col];
    }
    __syncthreads();
    #pragma unroll
    for (int it = 0; it < 16; ++it) {
        int n = rg * 16 + it;
        float v = t_s[col][n];
        ushort h = bf16rne(v);
        float lo = v - bf16tof(h);
        dh[(nt * 64 + n) * HID + kt * 64 + col] = h;
        dl[(nt * 64 + n) * HID + kt * 64 + col] = bf16rne(lo);
    }
}

// ---------------------------------------------------------------------------
// K5c: wh_w1 -> W3h/W3l bf16 [l][n=256][k=512]; wh_w2 -> W4h/W4l bf16 [l][n][k].
__global__ void edm_k5c_prep(const float* __restrict__ wh_w1, const float* __restrict__ wh_w2,
                             ushort* __restrict__ W3h, ushort* __restrict__ W3l,
                             ushort* __restrict__ W4h, ushort* __restrict__ W4l)
{
    __shared__ float t_s[64][65];
    int blk = blockIdx.x;
    const float* src; ushort* dh; ushort* dl; int kt, nt, Kdim;
    if (blk < 288) {
        int l = blk >> 5, tile = blk & 31;
        kt = tile >> 2; nt = tile & 3; Kdim = 512;
        src = wh_w1 + (size_t)l * 512 * HID;
        dh = W3h + (size_t)l * HID * 512;
        dl = W3l + (size_t)l * HID * 512;
    } else {
        int b2 = blk - 288;
        int l = b2 >> 4, tile = b2 & 15;
        kt = tile >> 2; nt = tile & 3; Kdim = 256;
        src = wh_w2 + (size_t)l * HID * HID;
        dh = W4h + (size_t)l * HID * HID;
        dl = W4l + (size_t)l * HID * HID;
    }
    int col = threadIdx.x & 63, rg = threadIdx.x >> 6;
    #pragma unroll
    for (int it = 0; it < 16; ++it) {
        int row = rg * 16 + it;
        t_s[row][col] = src[(size_t)(kt * 64 + row) * HID + nt * 64 + col];
    }
    __syncthreads();
    #pragma unroll
    for (int it = 0; it < 16; ++it) {
        int n = rg * 16 + it;
        float v = t_s[col][n];
        ushort h = bf16rne(v);
        float lo = v - bf16tof(h);
        dh[(size_t)(nt * 64 + n) * Kdim + kt * 64 + col] = h;
        dl[(size_t)(nt * 64 + n) * Kdim + kt * 64 + col] = bf16rne(lo);
    }
}

// ---------------------------------------------------------------------------
// K1 (MFMA): HeA/HeB/HxA/HxB = h @ W1-slice (+bias) via bf16 hi/lo split.
__global__ __launch_bounds__(256)
void edm_k1_mfma(const float* __restrict__ h,
                 const ushort* __restrict__ W1Th, const ushort* __restrict__ W1Tl,
                 const float* __restrict__ we_b1, const float* __restrict__ wx_b1,
                 const float* __restrict__ we_w2, const float* __restrict__ we_b2,
                 const float* __restrict__ attn_w, const float* __restrict__ attn_b,
                 float* __restrict__ HeA, float* __restrict__ HeB,
                 float* __restrict__ HxA, float* __restrict__ HxB,
                 float* __restrict__ self_em, int l)
{
    int tid = threadIdx.x;
    if (blockIdx.x == 512) {
        __shared__ float m1s[HID];
        __shared__ float ms[HID];
        __shared__ float wred[4];
        __shared__ float gsh;
        const float* eb1 = we_b1 + l * HID;
        m1s[tid] = silu_f(eb1[tid]);
        __syncthreads();
        const float* W2 = we_w2 + l * HID * HID;
        float acc = we_b2[l * HID + tid];
        for (int k = 0; k < HID; ++k) acc += m1s[k] * W2[k * HID + tid];
        float mv = silu_f(acc);
        ms[tid] = mv;
        float p = mv * attn_w[l * HID + tid];
        #pragma unroll
        for (int off = 32; off > 0; off >>= 1) p += __shfl_down(p, off, 64);
        if ((tid & 63) == 0) wred[tid >> 6] = p;
        __syncthreads();
        if (tid == 0) gsh = sigm_f(wred[0] + wred[1] + wred[2] + wred[3] + attn_b[l]);
        __syncthreads();
        self_em[tid] = gsh * ms[tid];
        return;
    }

    __shared__ __align__(16) ushort Ah_s[16384];
    __shared__ __align__(16) ushort Al_s[16384];

    const int cq = blockIdx.x & 3;
    const int out = (blockIdx.x >> 2) & 3;
    const int ntile = blockIdx.x >> 4;
    const int base = ntile * 64;

    {
        const int c  = tid & 31;
        const int jg = tid >> 5;
        const int k0 = c * 8;
        #pragma unroll
        for (int it = 0; it < 8; ++it) {
            int m = it * 8 + jg;
            f32x4 h0 = *(const f32x4*)&h[(base + m) * HID + k0];
            f32x4 h1 = *(const f32x4*)&h[(base + m) * HID + k0 + 4];
            uint4 phi, plo;
            {
                ushort ax = bf16rne(h0.x), ay = bf16rne(h0.y);
                phi.x = (unsigned)ax | ((unsigned)ay << 16);
                plo.x = pk2((f32x2){h0.x - bf16tof(ax), h0.y - bf16tof(ay)});
            }
            {
                ushort ax = bf16rne(h0.z), ay = bf16rne(h0.w);
                phi.y = (unsigned)ax | ((unsigned)ay << 16);
                plo.y = pk2((f32x2){h0.z - bf16tof(ax), h0.w - bf16tof(ay)});
            }
            {
                ushort ax = bf16rne(h1.x), ay = bf16rne(h1.y);
                phi.z = (unsigned)ax | ((unsigned)ay << 16);
                plo.z = pk2((f32x2){h1.x - bf16tof(ax), h1.y - bf16tof(ay)});
            }
            {
                ushort ax = bf16rne(h1.z), ay = bf16rne(h1.w);
                phi.w = (unsigned)ax | ((unsigned)ay << 16);
                plo.w = pk2((f32x2){h1.z - bf16tof(ax), h1.w - bf16tof(ay)});
            }
            unsigned off = (unsigned)(m * 256 + ((c ^ (m & 7)) * 8));
            *(uint4*)&Ah_s[off] = phi;
            *(uint4*)&Al_s[off] = plo;
        }
    }
    __syncthreads();

    const int w = tid >> 6, lane = tid & 63, quad = lane >> 4, l16 = lane & 15;
    const int col = cq * 64 + w * 16 + l16;
    const ushort* Bh = W1Th + ((size_t)(l * 4 + out)) * HID * HID + (size_t)col * HID;
    const ushort* Bl = W1Tl + ((size_t)(l * 4 + out)) * HID * HID + (size_t)col * HID;

    f32x4 acc[4];
    #pragma unroll
    for (int mt = 0; mt < 4; ++mt) acc[mt] = (f32x4){0.f, 0.f, 0.f, 0.f};

    #pragma unroll
    for (int kt = 0; kt < 8; ++kt) {
        const int kof = kt * 32 + quad * 8;
        const int ch  = (kt * 4 + quad) ^ (l16 & 7);
        bfrag bh = *(const bfrag*)&Bh[kof];
        bfrag bl = *(const bfrag*)&Bl[kof];
        bfrag ahr[4], alr[4];
        #pragma unroll
        for (int mt = 0; mt < 4; ++mt) {
            ahr[mt] = *(const bfrag*)&Ah_s[(mt * 16 + l16) * 256 + ch * 8];
            alr[mt] = *(const bfrag*)&Al_s[(mt * 16 + l16) * 256 + ch * 8];
        }
        #pragma unroll
        for (int mt = 0; mt < 4; ++mt) {
            acc[mt] = __builtin_amdgcn_mfma_f32_16x16x32_bf16(ahr[mt], bh, acc[mt], 0, 0, 0);
            acc[mt] = __builtin_amdgcn_mfma_f32_16x16x32_bf16(ahr[mt], bl, acc[mt], 0, 0, 0);
            acc[mt] = __builtin_amdgcn_mfma_f32_16x16x32_bf16(alr[mt], bh, acc[mt], 0, 0, 0);
        }
    }

    float bias = 0.f;
    if (out == 0) bias = we_b1[l * HID + col];
    else if (out == 2) bias = wx_b1[l * HID + col];
    float* dst = (out == 0) ? HeA : (out == 1) ? HeB : (out == 2) ? HxA : HxB;
    #pragma unroll
    for (int mt = 0; mt < 4; ++mt)
        #pragma unroll
        for (int r = 0; r < 4; ++r)
            dst[(base + mt * 16 + quad * 4 + r) * HID + col] = acc[mt][r] + bias;
}

// ---------------------------------------------------------------------------
// KB: fused m1-recompute + MFMA GEMM + epilogue. grid 4096 = pass(2) x 2048.
// Block remap for XCD L2 locality: i in HIGH bits -> all 64 i-blocks of (p,b)
// share blk%8 -> one XCD caches batch b's HeB/HxB tile.
__global__ __launch_bounds__(256, 4)
void edm_kb_gemm(const float* __restrict__ x_cur, float* __restrict__ x_next,
                 const float* __restrict__ HeA, const float* __restrict__ HeB,
                 const float* __restrict__ HxA, const float* __restrict__ HxB,
                 const float* __restrict__ din_ws,
                 const float* __restrict__ we_w1, const float* __restrict__ we_b1,
                 const float* __restrict__ wx_w1, const float* __restrict__ wx_b1,
                 const ushort* __restrict__ W2Te, const ushort* __restrict__ W2Tx,
                 const float* __restrict__ we_b2, const float* __restrict__ wx_b2,
                 const float* __restrict__ attn_w, const float* __restrict__ attn_b,
                 const float* __restrict__ wx_w3,
                 float* __restrict__ em_agg, int l)
{
    __shared__ __align__(16) ushort A_s[16384];
    __shared__ float red_s[256];
    __shared__ float sc_s[64];
    __shared__ float x_s[192];
    __shared__ float d2_s[64], din_s[64];

    const int tid = threadIdx.x;
    const int blk = blockIdx.x;
    const int p = blk >> 11, rem = blk & 2047;
    const int i = rem >> 5, b = rem & 31;            // i in high bits (XCD locality)
    const int bi = b * 64 + i;

    // single-barrier preamble: x_s staging and d2/din computed in parallel
    if (tid < 192) x_s[tid] = x_cur[b * 192 + tid];
    if (tid >= 192) {
        int j = tid - 192;                           // 0..63
        float d0 = x_cur[b * 192 + i*3+0] - x_cur[b * 192 + j*3+0];
        float d1 = x_cur[b * 192 + i*3+1] - x_cur[b * 192 + j*3+1];
        float d2 = x_cur[b * 192 + i*3+2] - x_cur[b * 192 + j*3+2];
        float ss = d0*d0 + d1*d1 + d2*d2;
        float d  = sqrtf(fmaxf(ss, 1e-12f));
        d2_s[j]  = d * d;
        din_s[j] = din_ws[b * EPB + i * 64 + j];
    }
    __syncthreads();

    {
        const float* W1  = (p ? wx_w1 : we_w1) + l * 514 * HID;
        const float* HA  = (p ? HxA : HeA);
        const float* HB  = (p ? HxB : HeB);
        const float* b1p = (p ? wx_b1 : we_b1) + l * HID;

        const int c  = tid & 31;
        const int jg = tid >> 5;
        const int k0 = c * 8;

        f32x4 ra0 = *(const f32x4*)&HA[(b * 64 + i) * HID + k0];
        f32x4 ra1 = *(const f32x4*)&HA[(b * 64 + i) * HID + k0 + 4];
        f32x4 wa0 = *(const f32x4*)&W1[512 * HID + k0];
        f32x4 wa1 = *(const f32x4*)&W1[512 * HID + k0 + 4];
        f32x4 wb0 = *(const f32x4*)&W1[513 * HID + k0];
        f32x4 wb1 = *(const f32x4*)&W1[513 * HID + k0 + 4];
        f32x4 b10 = *(const f32x4*)&b1p[k0];
        f32x4 b11 = *(const f32x4*)&b1p[k0 + 4];
        uint4 pki;
        pki.x = pk2(silu2((f32x2){b10.x, b10.y}));
        pki.y = pk2(silu2((f32x2){b10.z, b10.w}));
        pki.z = pk2(silu2((f32x2){b11.x, b11.y}));
        pki.w = pk2(silu2((f32x2){b11.z, b11.w}));

        const float* hbp = HB + b * 64 * HID + k0;
        #pragma unroll
        for (int it = 0; it < 8; ++it) {
            int j = it * 8 + jg;
            f32x4 h0 = *(const f32x4*)&hbp[j * HID];
            f32x4 h1 = *(const f32x4*)&hbp[j * HID + 4];
            f32x2 dd = { d2_s[j], d2_s[j] };
            f32x2 dn = { din_s[j], din_s[j] };
            uint4 pkv;
            f32x2 v;
            v = fma2(dn, (f32x2){wb0.x, wb0.y},
                 fma2(dd, (f32x2){wa0.x, wa0.y},
                      (f32x2){ra0.x + h0.x, ra0.y + h0.y}));
            pkv.x = pk2(silu2(v));
            v = fma2(dn, (f32x2){wb0.z, wb0.w},
                 fma2(dd, (f32x2){wa0.z, wa0.w},
                      (f32x2){ra0.z + h0.z, ra0.w + h0.w}));
            pkv.y = pk2(silu2(v));
            v = fma2(dn, (f32x2){wb1.x, wb1.y},
                 fma2(dd, (f32x2){wa1.x, wa1.y},
                      (f32x2){ra1.x + h1.x, ra1.y + h1.y}));
            pkv.z = pk2(silu2(v));
            v = fma2(dn, (f32x2){wb1.z, wb1.w},
                 fma2(dd, (f32x2){wa1.z, wa1.w},
                      (f32x2){ra1.z + h1.z, ra1.w + h1.w}));
            pkv.w = pk2(silu2(v));
            if (j == i) pkv = pki;
            *(uint4*)&A_s[j * 256 + (unsigned)((c ^ (j & 7)) * 8)] = pkv;
        }
    }
    __syncthreads();

    const int w = tid >> 6, lane = tid & 63, quad = lane >> 4, l16 = lane & 15;
    const ushort* W2T = (p ? W2Tx : W2Te) + l * HID * HID;
    const int cb0 = w * 64 + l16;
    f32x4 acc[4][4];
    #pragma unroll
    for (int mt = 0; mt < 4; ++mt)
        #pragma unroll
        for (int nt = 0; nt < 4; ++nt) acc[mt][nt] = (f32x4){0.f, 0.f, 0.f, 0.f};

    #pragma unroll
    for (int kt = 0; kt < 8; ++kt) {
        const int kof = kt * 32 + quad * 8;
        const int ch  = (kt * 4 + quad) ^ (l16 & 7);
        bfrag bfr[4], afr[4];
        #pragma unroll
        for (int nt = 0; nt < 4; ++nt)
            bfr[nt] = *(const bfrag*)&W2T[(cb0 + nt * 16) * HID + kof];
        #pragma unroll
        for (int mt = 0; mt < 4; ++mt)
            afr[mt] = *(const bfrag*)&A_s[(mt * 16 + l16) * 256 + ch * 8];
        #pragma unroll
        for (int mt = 0; mt < 4; ++mt)
            #pragma unroll
            for (int nt = 0; nt < 4; ++nt)
                acc[mt][nt] = __builtin_amdgcn_mfma_f32_16x16x32_bf16(
                    afr[mt], bfr[nt], acc[mt][nt], 0, 0, 0);
    }

    const float* b2p = (p ? wx_b2 : we_b2) + l * HID;
    const float* vvp = p ? (wx_w3 + l * HID) : (attn_w + l * HID);
    float b2v[4], vv[4];
    #pragma unroll
    for (int nt = 0; nt < 4; ++nt) { b2v[nt] = b2p[cb0 + nt * 16]; vv[nt] = vvp[cb0 + nt * 16]; }

    #pragma unroll
    for (int mt = 0; mt < 4; ++mt)
        #pragma unroll
        for (int nt = 0; nt < 4; ++nt) {
            f32x4 bb = { b2v[nt], b2v[nt], b2v[nt], b2v[nt] };
            acc[mt][nt] = silu4(acc[mt][nt] + bb);
        }

    #pragma unroll
    for (int mt = 0; mt < 4; ++mt) {
        f32x4 t4 = acc[mt][0] * (f32x4){vv[0], vv[0], vv[0], vv[0]};
        t4 = fma4(acc[mt][1], (f32x4){vv[1], vv[1], vv[1], vv[1]}, t4);
        t4 = fma4(acc[mt][2], (f32x4){vv[2], vv[2], vv[2], vv[2]}, t4);
        t4 = fma4(acc[mt][3], (f32x4){vv[3], vv[3], vv[3], vv[3]}, t4);
        #pragma unroll
        for (int r = 0; r < 4; ++r) {
            float pd = t4[r];
            pd += __shfl_xor(pd, 1, 64); pd += __shfl_xor(pd, 2, 64);
            pd += __shfl_xor(pd, 4, 64); pd += __shfl_xor(pd, 8, 64);
            if (l16 == 0) red_s[w * 64 + mt * 16 + quad * 4 + r] = pd;
        }
    }
    __syncthreads();
    if (tid < 64) {
        float tot = red_s[tid] + red_s[64 + tid] + red_s[128 + tid] + red_s[192 + tid];
        if (p == 0) sc_s[tid] = (tid == i) ? 0.f : sigm_f(tot + attn_b[l]);
        else        sc_s[tid] = tot;
    }
    __syncthreads();

    if (p == 0) {
        f32x4 g[4];
        #pragma unroll
        for (int mt = 0; mt < 4; ++mt) g[mt] = *(const f32x4*)&sc_s[mt * 16 + quad * 4];
        #pragma unroll
        for (int nt = 0; nt < 4; ++nt) {
            f32x4 e4 = g[0] * acc[0][nt];
            e4 = fma4(g[1], acc[1][nt], e4);
            e4 = fma4(g[2], acc[2][nt], e4);
            e4 = fma4(g[3], acc[3][nt], e4);
            float e = (e4.x + e4.y) + (e4.z + e4.w);
            e += __shfl_xor(e, 16, 64); e += __shfl_xor(e, 32, 64);
            if (quad == 0) em_agg[(b * 64 + i) * HID + cb0 + nt * 16] = e;
        }
    } else {
        if (tid < 64) {
            int j = tid;
            float d0 = x_s[i*3+0] - x_s[j*3+0];
            float d1 = x_s[i*3+1] - x_s[j*3+1];
            float d2 = x_s[i*3+2] - x_s[j*3+2];
            float ss = d0*d0 + d1*d1 + d2*d2;
            float d  = sqrtf(fmaxf(ss, 1e-12f));
            float f  = fast_rcp(d + 1.f) * sc_s[j];
            float cx = d0 * f, cy = d1 * f, cz = d2 * f;
            #pragma unroll
            for (int off = 32; off > 0; off >>= 1) {
                cx += __shfl_down(cx, off, 64);
                cy += __shfl_down(cy, off, 64);
                cz += __shfl_down(cz, off, 64);
            }
            if (tid == 0) {
                x_next[bi * 3 + 0] = x_s[i*3+0] + cx;
                x_next[bi * 3 + 1] = x_s[i*3+1] + cy;
                x_next[bi * 3 + 2] = x_s[i*3+2] + cz;
            }
        }
    }
}

// ---------------------------------------------------------------------------
// K3a: u = silu(cat @ wh_w1 + b1), cat = [h | em_agg+self_em] (2048x512).
__global__ __launch_bounds__(256)
void edm_k3a(const float* __restrict__ h, const float* __restrict__ em_agg,
             const float* __restrict__ self_em,
             const ushort* __restrict__ W3h, const ushort* __restrict__ W3l,
             const float* __restrict__ wh_b1,
             ushort* __restrict__ Uh, ushort* __restrict__ Ul, int l)
{
    __shared__ __align__(16) ushort Ah_s[16 * 512];
    __shared__ __align__(16) ushort Al_s[16 * 512];

    const int tid = threadIdx.x;
    const int cq = blockIdx.x & 3;
    const int base = (blockIdx.x >> 2) * 16;

    {
        const int c  = tid & 63;
        const int jg = tid >> 6;
        const int k0 = c * 8;
        #pragma unroll
        for (int t = 0; t < 4; ++t) {
            int m = t * 4 + jg;
            f32x4 v0, v1;
            if (c < 32) {
                v0 = *(const f32x4*)&h[(base + m) * HID + k0];
                v1 = *(const f32x4*)&h[(base + m) * HID + k0 + 4];
            } else {
                int e0 = k0 - 256;
                f32x4 a0 = *(const f32x4*)&em_agg[(size_t)(base + m) * HID + e0];
                f32x4 a1 = *(const f32x4*)&em_agg[(size_t)(base + m) * HID + e0 + 4];
                f32x4 s0 = *(const f32x4*)&self_em[e0];
                f32x4 s1 = *(const f32x4*)&self_em[e0 + 4];
                v0 = a0 + s0; v1 = a1 + s1;
            }
            uint4 phi, plo;
            {
                ushort ax = bf16rne(v0.x), ay = bf16rne(v0.y);
                phi.x = (unsigned)ax | ((unsigned)ay << 16);
                plo.x = pk2((f32x2){v0.x - bf16tof(ax), v0.y - bf16tof(ay)});
            }
            {
                ushort ax = bf16rne(v0.z), ay = bf16rne(v0.w);
                phi.y = (unsigned)ax | ((unsigned)ay << 16);
                plo.y = pk2((f32x2){v0.z - bf16tof(ax), v0.w - bf16tof(ay)});
            }
            {
                ushort ax = bf16rne(v1.x), ay = bf16rne(v1.y);
                phi.z = (unsigned)ax | ((unsigned)ay << 16);
                plo.z = pk2((f32x2){v1.x - bf16tof(ax), v1.y - bf16tof(ay)});
            }
            {
                ushort ax = bf16rne(v1.z), ay = bf16rne(v1.w);
                phi.w = (unsigned)ax | ((unsigned)ay << 16);
                plo.w = pk2((f32x2){v1.z - bf16tof(ax), v1.w - bf16tof(ay)});
            }
            unsigned off = (unsigned)(m * 512 + ((c ^ (m & 7)) * 8));
            *(uint4*)&Ah_s[off] = phi;
            *(uint4*)&Al_s[off] = plo;
        }
    }
    __syncthreads();

    const int w = tid >> 6, lane = tid & 63, quad = lane >> 4, l16 = lane & 15;
    const int colv = cq * 64 + w * 16 + l16;

    f32x4 acc = (f32x4){0.f, 0.f, 0.f, 0.f};
    const ushort* Bh = W3h + ((size_t)l * HID + colv) * 512;
    const ushort* Bl = W3l + ((size_t)l * HID + colv) * 512;

    for (int ks = 0; ks < 16; ++ks) {
        const int kof = ks * 32 + quad * 8;
        unsigned aoff = (unsigned)(l16 * 512 + (((ks * 4 + quad) ^ (l16 & 7))) * 8);
        bfrag ah = *(const bfrag*)&Ah_s[aoff];
        bfrag al = *(const bfrag*)&Al_s[aoff];
        bfrag bh = *(const bfrag*)&Bh[kof];
        bfrag bl = *(const bfrag*)&Bl[kof];
        acc = __builtin_amdgcn_mfma_f32_16x16x32_bf16(ah, bh, acc, 0, 0, 0);
        acc = __builtin_amdgcn_mfma_f32_16x16x32_bf16(ah, bl, acc, 0, 0, 0);
        acc = __builtin_amdgcn_mfma_f32_16x16x32_bf16(al, bh, acc, 0, 0, 0);
    }

    float b1v = wh_b1[l * HID + colv];
    #pragma unroll
    for (int r = 0; r < 4; ++r) {
        float u = silu_f(acc[r] + b1v);
        ushort uh = bf16rne(u);
        float ulo = u - bf16tof(uh);
        int row = quad * 4 + r;
        size_t ao = (size_t)(base + row) * 256 + (((colv >> 3) ^ (row & 7))) * 8 + (colv & 7);
        Uh[ao] = uh;
        Ul[ao] = bf16rne(ulo);
    }
}

// ---------------------------------------------------------------------------
// K3b: h_next = h + u @ wh_w2 + b2, K=256. ZERO LDS; u from global (swizzled).
__global__ __launch_bounds__(256)
void edm_k3b(const float* __restrict__ h,
             const ushort* __restrict__ Uh, const ushort* __restrict__ Ul,
             const ushort* __restrict__ W4h, const ushort* __restrict__ W4l,
             const float* __restrict__ wh_b2,
             float* __restrict__ h_next, int l)
{
    const int tid = threadIdx.x;
    const int cq = blockIdx.x & 3;
    const int base = (blockIdx.x >> 2) * 16;
    const int w = tid >> 6, lane = tid & 63, quad = lane >> 4, l16 = lane & 15;
    const int colv = cq * 64 + w * 16 + l16;

    const ushort* Bh = W4h + ((size_t)l * HID + colv) * HID;
    const ushort* Bl = W4l + ((size_t)l * HID + colv) * HID;
    const ushort* Ah = Uh + (size_t)(base + l16) * 256;
    const ushort* Al = Ul + (size_t)(base + l16) * 256;

    f32x4 acc = (f32x4){0.f, 0.f, 0.f, 0.f};
    #pragma unroll
    for (int kt = 0; kt < 8; ++kt) {
        const int kof = kt * 32 + quad * 8;
        unsigned ach = (unsigned)((((kt * 4 + quad) ^ (l16 & 7))) * 8);
        bfrag ah = *(const bfrag*)&Ah[ach];
        bfrag al = *(const bfrag*)&Al[ach];
        bfrag bh = *(const bfrag*)&Bh[kof];
        bfrag bl = *(const bfrag*)&Bl[kof];
        acc = __builtin_amdgcn_mfma_f32_16x16x32_bf16(ah, bh, acc, 0, 0, 0);
        acc = __builtin_amdgcn_mfma_f32_16x16x32_bf16(ah, bl, acc, 0, 0, 0);
        acc = __builtin_amdgcn_mfma_f32_16x16x32_bf16(al, bh, acc, 0, 0, 0);
    }

    float b2v = wh_b2[l * HID + colv];
    #pragma unroll
    for (int r = 0; r < 4; ++r) {
        int node = base + quad * 4 + r;
        h_next[node * HID + colv] = h[node * HID + colv] + acc[r] + b2v;
    }
}

// ---------------------------------------------------------------------------
// K4: x_out = remove_mean(x - x_in); h_out = (h@wout_w + wout_b)[:, :5]
__global__ void edm_k4_out(const float* __restrict__ x_fin, const float* __restrict__ x_in,
                           const float* __restrict__ h_fin,
                           const float* __restrict__ wout_w, const float* __restrict__ wout_b,
                           float* __restrict__ out)
{
    __shared__ float vx[192];
    __shared__ float mean_s[3];
    int b = blockIdx.x, tid = threadIdx.x;
    if (tid < 192) vx[tid] = x_fin[b * 192 + tid] - x_in[b * 192 + tid];
    __syncthreads();
    if (tid < 3) {
        float s = 0.f;
        for (int n = 0; n < 64; ++n) s += vx[n * 3 + tid];
        mean_s[tid] = s * (1.f / 64.f);
    }
    __syncthreads();
    if (tid < 192) out[b * 512 + (tid / 3) * 8 + (tid % 3)] = vx[tid] - mean_s[tid % 3];

    int node = tid / 5, ch = tid % 5;
    float acc = wout_b[ch];
    const float* hr = h_fin + (b * 64 + node) * HID;
    for (int k = 0; k < HID; ++k) acc = fmaf(hr[k], wout_w[k * 6 + ch], acc);
    out[b * 512 + node * 8 + 3 + ch] = acc;
}

// ---------------------------------------------------------------------------
extern "C" void kernel_launch(void* const* d_in, const int* in_sizes, int n_in,
                              void* d_out, int out_size, void* d_ws, size_t ws_size,
                              hipStream_t stream)
{
    const float* x_in   = (const float*)d_in[0];
    const float* h_in   = (const float*)d_in[1];
    const float* t_in   = (const float*)d_in[2];
    const float* win_w  = (const float*)d_in[6];
    const float* win_b  = (const float*)d_in[7];
    const float* wout_w = (const float*)d_in[8];
    const float* wout_b = (const float*)d_in[9];
    const float* we_w1  = (const float*)d_in[10];
    const float* we_b1  = (const float*)d_in[11];
    const float* we_w2  = (const float*)d_in[12];
    const float* we_b2  = (const float*)d_in[13];
    const float* attn_w = (const float*)d_in[14];
    const float* attn_b = (const float*)d_in[15];
    const float* wh_w1  = (const float*)d_in[16];
    const float* wh_b1  = (const float*)d_in[17];
    const float* wh_w2  = (const float*)d_in[18];
    const float* wh_b2  = (const float*)d_in[19];
    const float* wx_w1  = (const float*)d_in[20];
    const float* wx_b1  = (const float*)d_in[21];
    const float* wx_w2  = (const float*)d_in[22];
    const float* wx_b2  = (const float*)d_in[23];
    const float* wx_w3  = (const float*)d_in[24];

    float* ws = (float*)d_ws;
    const size_t SN = (size_t)NB * NN * HID;     // 524288
    float* h_a = ws;
    float* h_b = ws + SN;
    float* HeA = ws + 2 * SN;
    float* HeB = ws + 3 * SN;
    float* HxA = ws + 4 * SN;
    float* HxB = ws + 5 * SN;
    float* emg = ws + 6 * SN;
    float* din = ws + 7 * SN;
    float* x_a = din + (size_t)NB * EPB;
    float* x_b = x_a + NB * NN * 3;
    float* sem = x_b + NB * NN * 3;
    ushort* W2Te = (ushort*)(sem + 256);
    ushort* W2Tx = W2Te + (size_t)NL * HID * HID;
    ushort* W1Th = W2Tx + (size_t)NL * HID * HID;
    ushort* W1Tl = W1Th + (size_t)NL * 4 * HID * HID;
    ushort* W3h  = W1Tl + (size_t)NL * 4 * HID * HID;
    ushort* W3l  = W3h + (size_t)NL * HID * 512;
    ushort* W4h  = W3l + (size_t)NL * HID * 512;
    ushort* W4l  = W4h + (size_t)NL * HID * HID;
    ushort* Uh   = W4l + (size_t)NL * HID * HID;
    ushort* Ul   = Uh + (size_t)NB * NN * HID;
    // total ws ~35 MB

    edm_k5_prep<<<dim3(288), dim3(256), 0, stream>>>(we_w2, wx_w2, W2Te, W2Tx);
    edm_k5b_prep<<<dim3(576), dim3(256), 0, stream>>>(we_w1, wx_w1, W1Th, W1Tl);
    edm_k5c_prep<<<dim3(432), dim3(256), 0, stream>>>(wh_w1, wh_w2, W3h, W3l, W4h, W4l);

    edm_k0_pre<<<dim3(NB * NN + 512 + 24), dim3(256), 0, stream>>>(
        x_in, h_in, t_in, win_w, win_b, h_a, din, x_a);

    for (int l = 0; l < NL; ++l) {
        float* h_cur = (l & 1) ? h_b : h_a;
        float* h_nxt = (l & 1) ? h_a : h_b;
        float* x_cur = (l & 1) ? x_b : x_a;
        float* x_nxt = (l & 1) ? x_a : x_b;

        edm_k1_mfma<<<dim3(513), dim3(256), 0, stream>>>(
            h_cur, W1Th, W1Tl, we_b1, wx_b1, we_w2, we_b2, attn_w, attn_b,
            HeA, HeB, HxA, HxB, sem, l);

        edm_kb_gemm<<<dim3(2 * NB * NN), dim3(256), 0, stream>>>(
            x_cur, x_nxt, HeA, HeB, HxA, HxB, din,
            we_w1, we_b1, wx_w1, wx_b1, W2Te, W2Tx,
            we_b2, wx_b2, attn_w, attn_b, wx_w3, emg, l);

        edm_k3a<<<dim3(512), dim3(256), 0, stream>>>(
            h_cur, emg, sem, W3h, W3l, wh_b1, Uh, Ul, l);

        edm_k3b<<<dim3(512), dim3(256), 0, stream>>>(
            h_cur, Uh, Ul, W4h, W4l, wh_b2, h_nxt, l);
    }

    edm_k4_out<<<dim3(NB), dim3(320), 0, stream>>>(
        x_b, x_in, h_b, wout_w, wout_b, (float*)d_out);
}